// Round 9
// baseline (30861.130 us; speedup 1.0000x reference)
//
#include <hip/hip_runtime.h>
#include <cstdint>
#include <cstddef>

// Problem constants
#define T_STEPS 8192
#define IN_DIM  1024
#define HID     1024
#define OUT_DIM 1024

// R17: wave specialization. Model (fixed by R15's full-duration sleep add):
// the spin succeeds on its FIRST check -- no quantization tail, no wasted
// sweeps -- so period = s(shadow ~450cy) + L(poll flight) + B + E, and the
// only removable term without touching the spin is s. The shadow work
// (y_{t-1}, pp_{t+1}, x prefetch) has NO dependence on the spin result, so
// it moves to a dedicated 5th wave that runs during the others' spin-wait.
// Waves 0-3: R12's critical loop with EMPTY shadow (publish -> poll issue
// immediately). Wave 4: y (out_w pinned in its regs) + x load + all 16
// pp rows -> double-buffered pplds; compute waves read pp in E (4 LDS
// reads). Handoffs ride the existing raw barrier. s_sleep 8 keeps the
// shadow wave off wave 0's SIMD during E.
// History: R10 -43% (stagger vmcnt serialization); R13 -50% (predicated
// spin serialized); R14 -13% (2 waves/SIMD doubled E); R15 -29% (sleep
// added fully => first-check-success regime); R16 -37% (2 units/wave
// widened E+s). Wins: R9 fusion, R12 prefetch double-buffer. Spin inner
// structure (uniform loads, single drain, __all) is load-bearing.
#define NBLK 256
#define TPB  320   // 4 compute waves + 1 shadow wave
#define UPB  4     // units per block (1 per compute wave)

typedef __attribute__((ext_vector_type(4))) float f32x4;

#define PLOAD(p) __hip_atomic_load((p), __ATOMIC_RELAXED, __HIP_MEMORY_SCOPE_AGENT)

__device__ __forceinline__ float sigf(float x) {
  return 1.0f / (1.0f + __expf(-x));
}

template<int CTRL>
__device__ __forceinline__ float dpp_add(float v) {
  int p = __builtin_amdgcn_update_dpp(0, __float_as_int(v), CTRL, 0xf, 0xf, true);
  return v + __int_as_float(p);
}

// Full 64-lane sum, all-VALU (DPP). Result valid in LANE 63 only.
__device__ __forceinline__ float wave_sum63(float v) {
  v = dpp_add<0xB1>(v);    // quad_perm [1,0,3,2]
  v = dpp_add<0x4E>(v);    // quad_perm [2,3,0,1]
  v = dpp_add<0x141>(v);   // row_half_mirror
  v = dpp_add<0x140>(v);   // row_mirror
  v = dpp_add<0x142>(v);   // row_bcast15
  v = dpp_add<0x143>(v);   // row_bcast31
  return v;
}

// ---------------------------------------------------------------------------
// Fused persistent LSTM, wave-specialized. hbuf: [2][1024] u64 {tag, h}.
// Compute wave (wslot 0..3), iteration t = 0..T:
//   B) spin on my 256-chunk of slot t&1 for tag t (R12 shape, untouched)
//   C) deposit into lh[t&1]; raw barrier (lgkmcnt only)      <- C(t)
//   D) hv from LDS; pp (4 floats) from pplds[t&1]
//   E) [t<T] 64 FMA + 4 DPP reduces -> lane 63: acts, c, h, publish t+1
//   loop (nothing else -- s ~= 0)
// Shadow wave (wslot 4), iteration t = 0..T:
//   raw barrier C(t); s_sleep 8 (dodge E on the shared SIMD);
//   hv from lh[t&1];
//   [t>0] y_{t-1} = out_w[ub+q].hv for q=0..3 (+reduce), lane63 stores;
//   [t+1<T] load x[t+1]; pp rows m=0..15 -> pplds[(t+1)&1]
// Race freedom: pplds[(t+1)&1] written in round t is read in round t+1
// after C(t+1) (barrier-ordered); the same buffer's previous read (E(t-1))
// completed before C(t) (program order). lh as before. Skew safety of the
// tag protocol unchanged from R12 (every block consumes full h per step).
// ---------------------------------------------------------------------------
__global__ __launch_bounds__(TPB, 1) void lstm_fused(
    const float* __restrict__ Ww,                 // [4096, 2048]
    const float* __restrict__ xg,                 // [T, 1024]
    const float* __restrict__ owm,                // [1024, 1024]
    const float* __restrict__ wb,                 // [4096]
    const float* __restrict__ obv,                // [1024]
    unsigned long long* __restrict__ hbuf,        // [2][1024] tagged
    float* __restrict__ out)                      // [T, 1024]
{
  __shared__ float whlds[16][HID];     // 64 KB: W_h rows m = ul*4+g
  __shared__ float wxlds[16][HID];     // 64 KB: W_x rows, same layout
  __shared__ float lh[2][HID];         // 8 KB: staged h, double-buffered
  __shared__ float pplds[2][16][64];   // 8 KB: x-partials, double-buffered

  const int tid = threadIdx.x;
  const int lane = tid & 63;
  const int wslot = tid >> 6;          // 0..3 compute, 4 shadow
  const int ub = blockIdx.x * UPB;     // first unit of this block

  // Stage W_h and W_x rows for this block (float4, coalesced, all 5 waves).
  {
    const float4* __restrict__ Ww4 = (const float4*)Ww;  // row stride 512 f4
    float4* wh4 = (float4*)&whlds[0][0];
    float4* wx4 = (float4*)&wxlds[0][0];
    for (int i = tid; i < 16 * 256; i += TPB) {
      const int m = i >> 8;            // 0..15
      const int e4 = i & 255;
      const int gg = m & 3;
      const int ul = m >> 2;
      const size_t row = (size_t)(gg * HID + ub + ul) * 512;
      wh4[i] = Ww4[row + (IN_DIM / 4) + e4];   // recurrent half
      wx4[i] = Ww4[row + e4];                  // input half
    }
  }
  __syncthreads();

  if (wslot < UPB) {
    // ================= COMPUTE WAVE =================
    const int u = ub + wslot;
    const f32x4* wl4 = (const f32x4*)&whlds[wslot * 4][0];

    f32x4 W[16];
#pragma unroll
    for (int r = 0; r < 4; ++r)
#pragma unroll
      for (int k = 0; k < 4; ++k)
        W[r * 4 + k] = wl4[r * 256 + k * 64 + lane];
#pragma unroll
    for (int i = 0; i < 16; ++i) asm volatile("" : "+v"(W[i]));

    const float bi = wb[u],           bf = wb[HID + u];
    const float bg = wb[2 * HID + u], bo = wb[3 * HID + u];

    __syncthreads();   // pairs with shadow's post-pp(0) sync

    float c = 0.0f;

    for (int t = 0; t <= T_STEPS; ++t) {
      // B) spin: only vmem of the iteration besides the publish store.
      const unsigned long long* hs = hbuf + (size_t)(t & 1) * HID + wslot * 256;
      const unsigned want = (unsigned)t;
      unsigned long long p0, p1, p2, p3;
      for (;;) {
        p0 = PLOAD(hs + lane);
        p1 = PLOAD(hs + 64 + lane);
        p2 = PLOAD(hs + 128 + lane);
        p3 = PLOAD(hs + 192 + lane);
        bool ok = ((unsigned)p0 == want) & ((unsigned)p1 == want) &
                  ((unsigned)p2 == want) & ((unsigned)p3 == want);
        if (__all((int)ok)) break;
      }
      {
        float* dst = &lh[t & 1][wslot * 256];
        dst[lane]       = __uint_as_float((unsigned)(p0 >> 32));
        dst[64 + lane]  = __uint_as_float((unsigned)(p1 >> 32));
        dst[128 + lane] = __uint_as_float((unsigned)(p2 >> 32));
        dst[192 + lane] = __uint_as_float((unsigned)(p3 >> 32));
      }

      // C) raw barrier: LDS drain only; vmem stays in flight.
      asm volatile("s_waitcnt lgkmcnt(0)\n\ts_barrier" ::: "memory");

      // D) h_{t-1} + my pp from LDS
      const f32x4* lhp = (const f32x4*)&lh[t & 1][0];
      f32x4 hv[4];
#pragma unroll
      for (int k = 0; k < 4; ++k) hv[k] = lhp[k * 64 + lane];

      // E) gates -> h_t -> publish
      if (t < T_STEPS) {
        const float* ppb = &pplds[t & 1][wslot * 4][0];
        float a[4];
#pragma unroll
        for (int r = 0; r < 4; ++r) {
          float s = ppb[r * 64 + lane];   // x-partial seeds the chain
#pragma unroll
          for (int k = 0; k < 4; ++k) {
            s = fmaf(W[r*4+k].x, hv[k].x, s); s = fmaf(W[r*4+k].y, hv[k].y, s);
            s = fmaf(W[r*4+k].z, hv[k].z, s); s = fmaf(W[r*4+k].w, hv[k].w, s);
          }
          a[r] = wave_sum63(s);
        }
        const float gi = a[0] + bi, gf = a[1] + bf, gc = a[2] + bg, go = a[3] + bo;
        const float si = sigf(gi), sf = sigf(gf), so = sigf(go);
        const float tg = fmaf(2.0f, sigf(2.0f * gc), -1.0f);   // tanh
        c = fmaf(sf, c, si * tg);
        const float h = so * fmaf(2.0f, sigf(2.0f * c), -1.0f);
        if (lane == 63) {
          const unsigned long long pk =
              ((unsigned long long)__float_as_uint(h) << 32) | (unsigned)(t + 1);
          __hip_atomic_store(hbuf + (size_t)((t + 1) & 1) * HID + u, pk,
                             __ATOMIC_RELAXED, __HIP_MEMORY_SCOPE_AGENT);
        }
      }
      // s ~= 0: straight back to the spin. Keep publish above the poll loads.
      __builtin_amdgcn_sched_barrier(0);
    }
  } else {
    // ================= SHADOW WAVE =================
    f32x4 O[16];
#pragma unroll
    for (int q = 0; q < 4; ++q) {
      const f32x4* ow4 = (const f32x4*)(owm + (size_t)(ub + q) * HID);
#pragma unroll
      for (int k = 0; k < 4; ++k) O[q * 4 + k] = ow4[k * 64 + lane];
    }
#pragma unroll
    for (int i = 0; i < 16; ++i) asm volatile("" : "+v"(O[i]));

    float oby[4];
#pragma unroll
    for (int q = 0; q < 4; ++q) oby[q] = obv[ub + q];

    // pp(0) -> pplds[0]
    {
      const f32x4* xt4 = (const f32x4*)xg;
      f32x4 xv[4];
#pragma unroll
      for (int k = 0; k < 4; ++k) xv[k] = xt4[k * 64 + lane];
#pragma unroll
      for (int m = 0; m < 16; ++m) {
        const f32x4* wxm = (const f32x4*)&wxlds[m][0];
        float s = 0.0f;
#pragma unroll
        for (int k = 0; k < 4; ++k) {
          const f32x4 wx = wxm[k * 64 + lane];
          s = fmaf(wx.x, xv[k].x, s); s = fmaf(wx.y, xv[k].y, s);
          s = fmaf(wx.z, xv[k].z, s); s = fmaf(wx.w, xv[k].w, s);
        }
        pplds[0][m][lane] = s;
      }
    }
    __syncthreads();   // pp(0) visible before compute's first E

    for (int t = 0; t <= T_STEPS; ++t) {
      // C(t): same raw barrier as the compute waves.
      asm volatile("s_waitcnt lgkmcnt(0)\n\ts_barrier" ::: "memory");
      // Let wave 0's E issue uncontended on the shared SIMD (~512cy).
      asm volatile("s_sleep 8" ::: "memory");

      const f32x4* lhp = (const f32x4*)&lh[t & 1][0];
      f32x4 hv[4];
#pragma unroll
      for (int k = 0; k < 4; ++k) hv[k] = lhp[k * 64 + lane];

      // y_{t-1} for the block's 4 units (runs under the others' spin-wait)
      if (t > 0) {
#pragma unroll
        for (int q = 0; q < 4; ++q) {
          float yv = 0.0f;
#pragma unroll
          for (int k = 0; k < 4; ++k) {
            yv = fmaf(O[q*4+k].x, hv[k].x, yv); yv = fmaf(O[q*4+k].y, hv[k].y, yv);
            yv = fmaf(O[q*4+k].z, hv[k].z, yv); yv = fmaf(O[q*4+k].w, hv[k].w, yv);
          }
          yv = wave_sum63(yv);
          if (lane == 63) out[(size_t)(t - 1) * OUT_DIM + ub + q] = yv + oby[q];
        }
      }

      // pp(t+1) -> pplds[(t+1)&1]; budget ~2700cy, work ~1300cy.
      if (t + 1 < T_STEPS) {
        const f32x4* xt4 = (const f32x4*)(xg + (size_t)(t + 1) * IN_DIM);
        f32x4 xv[4];
#pragma unroll
        for (int k = 0; k < 4; ++k) xv[k] = xt4[k * 64 + lane];
#pragma unroll
        for (int m = 0; m < 16; ++m) {
          const f32x4* wxm = (const f32x4*)&wxlds[m][0];
          float s = 0.0f;
#pragma unroll
          for (int k = 0; k < 4; ++k) {
            const f32x4 wx = wxm[k * 64 + lane];
            s = fmaf(wx.x, xv[k].x, s); s = fmaf(wx.y, xv[k].y, s);
            s = fmaf(wx.z, xv[k].z, s); s = fmaf(wx.w, xv[k].w, s);
          }
          pplds[(t + 1) & 1][m][lane] = s;
        }
      }
    }
  }
}

// ---------------------------------------------------------------------------
// Workspace layout (bytes): [0, 16K) : hbuf[2][1024] tagged u64 (memset 0)
// ---------------------------------------------------------------------------
extern "C" void kernel_launch(void* const* d_in, const int* in_sizes, int n_in,
                              void* d_out, int out_size, void* d_ws, size_t ws_size,
                              hipStream_t stream) {
  (void)in_sizes; (void)n_in; (void)out_size; (void)ws_size;

  const float* x     = (const float*)d_in[0];  // [T,1,IN]
  const float* W_w   = (const float*)d_in[1];  // [4096, 2048]
  const float* W_b   = (const float*)d_in[2];  // [4096]
  const float* out_w = (const float*)d_in[3];  // [1024, 1024]
  const float* out_b = (const float*)d_in[4];  // [1024]
  float* out = (float*)d_out;                  // [T,1,1024]

  unsigned long long* hbuf = (unsigned long long*)d_ws;
  hipMemsetAsync(d_ws, 0, 16384, stream);

  lstm_fused<<<NBLK, TPB, 0, stream>>>(W_w, x, out_w, W_b, out_b, hbuf, out);
}

// Round 10
// 11630.389 us; speedup vs baseline: 2.6535x; 2.6535x over previous
//
#include <hip/hip_runtime.h>
#include <cstdint>
#include <cstddef>

// Problem constants
#define T_STEPS 8192
#define IN_DIM  1024
#define HID     1024
#define OUT_DIM 1024
#define G4      4096   // 4*HID

// R18 == R12 restore (11.62ms, session best). Session synthesis:
//   period(3400cy) = s(shadow ~450, FREE: hides in F) + F(agent-atomic L3
//   roundtrip ~2300) + B(barrier ~250) + E(gates ~400).
// Verified by: R15 (any added delay adds FULLY -- self-synchronized loop);
// R14/R16 (halved poll traffic: no latency change -- F is latency not
// bandwidth); R10/R17 (polling early / jittery pacing -> reads hit L3
// before peer publishes land -> line bouncing, FETCH 3x, collapse);
// R13 (predicated spin serializes the sweep). The spin's inner structure
// (uniform loads, single drain, __all) and the ~450cy publish->poll gap
// are both load-bearing. F is the cross-XCD coherence latency of relaxed
// agent atomics -- not reachable from schedule/traffic/geometry. Wins kept:
// R9 (full fusion: GEMMs folded into the wait shadow), R12 (x-prefetch
// double-buffer so the spin's vmcnt(0) drain is free).
#define NBLK 256
#define TPB  256
#define UPB  4    // units per block (1 per wave)

typedef __attribute__((ext_vector_type(4))) float f32x4;

#define PLOAD(p) __hip_atomic_load((p), __ATOMIC_RELAXED, __HIP_MEMORY_SCOPE_AGENT)

__device__ __forceinline__ float sigf(float x) {
  return 1.0f / (1.0f + __expf(-x));
}

template<int CTRL>
__device__ __forceinline__ float dpp_add(float v) {
  int p = __builtin_amdgcn_update_dpp(0, __float_as_int(v), CTRL, 0xf, 0xf, true);
  return v + __int_as_float(p);
}

// Full 64-lane sum, all-VALU (DPP). Result valid in LANE 63 only.
__device__ __forceinline__ float wave_sum63(float v) {
  v = dpp_add<0xB1>(v);    // quad_perm [1,0,3,2]
  v = dpp_add<0x4E>(v);    // quad_perm [2,3,0,1]
  v = dpp_add<0x141>(v);   // row_half_mirror
  v = dpp_add<0x140>(v);   // row_mirror
  v = dpp_add<0x142>(v);   // row_bcast15
  v = dpp_add<0x143>(v);   // row_bcast31
  return v;
}

// ---------------------------------------------------------------------------
// Fused persistent LSTM: tagged dataflow (no device barrier), LDS-resident
// W_h and W_x, reg-resident out_w row. hbuf: [2][1024] u64 {lo=tag, hi=h}.
// Iteration t (t = 0..T inclusive):
//   B) spin on my 256-chunk of slot t&1 for tag t (4 uniform loads,
//      single drain, __all)
//   C) deposit into lh[t&1]; raw barrier (lgkmcnt only; vmem in flight)
//   D) hv = full h_{t-1} from LDS
//   E) [t<T] gates: chain init = pp[] (x-partials), 64 FMA vs reg-pinned
//      W_h, DPP reduce -> lane 63: acts, c, h, publish tag t+1
//   -- sched_barrier: nothing below may delay the publish --
//   X) [t+2<T] issue x[t+2] prefetch into xnN (double-buffer: retires
//      during the next spin, so its vmcnt(0) drain is ~free)
//   F) [t>0] y_{t-1} = out_w[u].hv (+DPP reduce), lane 63 stores out[t-1]
//   G) [t+1<T] pp[] = partials of W_x . x_{t+1} from xnP (retired long ago)
//   R) xnP <= xnN (register rotate)
// Skew safety: every wave consumes the FULL h each step via its chunk +
// barrier; tag t+2 publish implies all waves passed poll t+1, so depth-2
// slots never skip a tag. Publish stores are never vmcnt-drained in-loop;
// pollers enforce visibility.
// ---------------------------------------------------------------------------
__global__ __launch_bounds__(TPB, 1) void lstm_fused(
    const float* __restrict__ Ww,                 // [4096, 2048]
    const float* __restrict__ xg,                 // [T, 1024]
    const float* __restrict__ owm,                // [1024, 1024]
    const float* __restrict__ wb,                 // [4096]
    const float* __restrict__ obv,                // [1024]
    unsigned long long* __restrict__ hbuf,        // [2][1024] tagged
    float* __restrict__ out)                      // [T, 1024]
{
  __shared__ float whlds[16][HID];  // 64 KB: W_h rows m = ul*4+g
  __shared__ float wxlds[16][HID];  // 64 KB: W_x rows, same layout
  __shared__ float lh[2][HID];      // 8 KB: staged h, double-buffered

  const int tid = threadIdx.x;
  const int lane = tid & 63;
  const int wslot = tid >> 6;                 // 0..3 = unit-in-block
  const int u = blockIdx.x * UPB + wslot;     // this wave's hidden unit

  // Stage W_h and W_x rows for this block (float4, coalesced).
  {
    const float4* __restrict__ Ww4 = (const float4*)Ww;  // row stride 512 f4
    float4* wh4 = (float4*)&whlds[0][0];
    float4* wx4 = (float4*)&wxlds[0][0];
    for (int i = tid; i < 16 * 256; i += TPB) {
      const int m = i >> 8;            // 0..15
      const int e4 = i & 255;          // float4 index within row
      const int gg = m & 3;
      const int ul = m >> 2;
      const size_t row = (size_t)(gg * HID + blockIdx.x * UPB + ul) * 512;
      wh4[i] = Ww4[row + (IN_DIM / 4) + e4];   // recurrent half
      wx4[i] = Ww4[row + e4];                  // input half
    }
  }
  __syncthreads();

  const f32x4* wl4 = (const f32x4*)&whlds[wslot * 4][0];
  const f32x4* wxl = (const f32x4*)&wxlds[wslot * 4][0];

  // Hoist W_h fragments into registers for the whole loop (loop-invariant).
  f32x4 W[16];
#pragma unroll
  for (int r = 0; r < 4; ++r)
#pragma unroll
    for (int k = 0; k < 4; ++k)
      W[r * 4 + k] = wl4[r * 256 + k * 64 + lane];
#pragma unroll
  for (int i = 0; i < 16; ++i) asm volatile("" : "+v"(W[i]));

  // out_w row for this unit, pinned (16 VGPRs).
  f32x4 O[4];
  {
    const f32x4* ow4 = (const f32x4*)(owm + (size_t)u * HID);
#pragma unroll
    for (int k = 0; k < 4; ++k) O[k] = ow4[k * 64 + lane];
#pragma unroll
    for (int k = 0; k < 4; ++k) asm volatile("" : "+v"(O[k]));
  }

  const float bi = wb[u],           bf = wb[HID + u];
  const float bg = wb[2 * HID + u], bo = wb[3 * HID + u];
  const float oby = obv[u];

  // Prologue: x-partials for step 0, and xnP = x[1] for step 0's G.
  float pp[4];
  {
    const f32x4* xt4 = (const f32x4*)xg;
    f32x4 x0[4];
#pragma unroll
    for (int k = 0; k < 4; ++k) x0[k] = xt4[k * 64 + lane];
#pragma unroll
    for (int r = 0; r < 4; ++r) {
      float s = 0.0f;
#pragma unroll
      for (int k = 0; k < 4; ++k) {
        const f32x4 wx = wxl[r * 256 + k * 64 + lane];
        s = fmaf(wx.x, x0[k].x, s); s = fmaf(wx.y, x0[k].y, s);
        s = fmaf(wx.z, x0[k].z, s); s = fmaf(wx.w, x0[k].w, s);
      }
      pp[r] = s;
    }
  }
  f32x4 xnP[4];
  {
    const f32x4* xt4 = (const f32x4*)(xg + (size_t)1 * IN_DIM);
#pragma unroll
    for (int k = 0; k < 4; ++k) xnP[k] = xt4[k * 64 + lane];
  }

  float c = 0.0f;

  for (int t = 0; t <= T_STEPS; ++t) {
    // B) spin: first vmem ops of the iteration (single-set form).
    const unsigned long long* hs = hbuf + (size_t)(t & 1) * HID + wslot * 256;
    const unsigned want = (unsigned)t;
    unsigned long long p0, p1, p2, p3;
    for (;;) {
      p0 = PLOAD(hs + lane);
      p1 = PLOAD(hs + 64 + lane);
      p2 = PLOAD(hs + 128 + lane);
      p3 = PLOAD(hs + 192 + lane);
      bool ok = ((unsigned)p0 == want) & ((unsigned)p1 == want) &
                ((unsigned)p2 == want) & ((unsigned)p3 == want);
      if (__all((int)ok)) break;
    }
    {
      float* dst = &lh[t & 1][wslot * 256];
      dst[lane]       = __uint_as_float((unsigned)(p0 >> 32));
      dst[64 + lane]  = __uint_as_float((unsigned)(p1 >> 32));
      dst[128 + lane] = __uint_as_float((unsigned)(p2 >> 32));
      dst[192 + lane] = __uint_as_float((unsigned)(p3 >> 32));
    }

    // C) raw barrier: drain LDS ops only; global loads/stores stay in flight
    asm volatile("s_waitcnt lgkmcnt(0)\n\ts_barrier" ::: "memory");

    // D) full h_{t-1} from LDS
    const f32x4* lhp = (const f32x4*)&lh[t & 1][0];
    f32x4 hv[4];
#pragma unroll
    for (int k = 0; k < 4; ++k) hv[k] = lhp[k * 64 + lane];

    // E) gates -> h_t -> publish (critical path; lane 63 is the publisher)
    if (t < T_STEPS) {
      float a[4];
#pragma unroll
      for (int r = 0; r < 4; ++r) {
        float s = pp[r];   // x-partial initializes the chain (summed by tree)
#pragma unroll
        for (int k = 0; k < 4; ++k) {
          s = fmaf(W[r*4+k].x, hv[k].x, s); s = fmaf(W[r*4+k].y, hv[k].y, s);
          s = fmaf(W[r*4+k].z, hv[k].z, s); s = fmaf(W[r*4+k].w, hv[k].w, s);
        }
        a[r] = wave_sum63(s);
      }
      // Only lane 63 holds real sums; other lanes compute garbage harmlessly.
      const float gi = a[0] + bi, gf = a[1] + bf, gc = a[2] + bg, go = a[3] + bo;
      const float si = sigf(gi), sf = sigf(gf), so = sigf(go);
      const float tg = fmaf(2.0f, sigf(2.0f * gc), -1.0f);   // tanh
      c = fmaf(sf, c, si * tg);
      const float h = so * fmaf(2.0f, sigf(2.0f * c), -1.0f);
      if (lane == 63) {
        const unsigned long long pk =
            ((unsigned long long)__float_as_uint(h) << 32) | (unsigned)(t + 1);
        __hip_atomic_store(hbuf + (size_t)((t + 1) & 1) * HID + u, pk,
                           __ATOMIC_RELAXED, __HIP_MEMORY_SCOPE_AGENT);
      }
    }

    // Nothing below may be scheduled above the publish.
    __builtin_amdgcn_sched_barrier(0);

    // X) x[t+2] prefetch: earliest vmem point after publish. Read-only
    // data -- no coherence pollution. Retires during the next spin, so its
    // drain is ~free.
    f32x4 xnN[4];
    const bool pf = (t + 2 < T_STEPS);
    if (pf) {
      const f32x4* xt4 = (const f32x4*)(xg + (size_t)(t + 2) * IN_DIM);
#pragma unroll
      for (int k = 0; k < 4; ++k) xnN[k] = xt4[k * 64 + lane];
    }

    // F) y_{t-1} = out_w[u] . h_{t-1} + out_b[u]; store also has a full
    // shadow+spin to retire before the next drain.
    if (t > 0) {
      float yv = 0.0f;
#pragma unroll
      for (int k = 0; k < 4; ++k) {
        yv = fmaf(O[k].x, hv[k].x, yv); yv = fmaf(O[k].y, hv[k].y, yv);
        yv = fmaf(O[k].z, hv[k].z, yv); yv = fmaf(O[k].w, hv[k].w, yv);
      }
      yv = wave_sum63(yv);
      if (lane == 63) out[(size_t)(t - 1) * OUT_DIM + u] = yv + oby;
    }
    __builtin_amdgcn_sched_barrier(0);

    // G) x-partials for step t+1 from xnP (issued a full step ago --
    // retired by this iteration's spin drain; never stalls).
    if (t + 1 < T_STEPS) {
#pragma unroll
      for (int r = 0; r < 4; ++r) {
        float s = 0.0f;
#pragma unroll
        for (int k = 0; k < 4; ++k) {
          const f32x4 wx = wxl[r * 256 + k * 64 + lane];
          s = fmaf(wx.x, xnP[k].x, s); s = fmaf(wx.y, xnP[k].y, s);
          s = fmaf(wx.z, xnP[k].z, s); s = fmaf(wx.w, xnP[k].w, s);
        }
        pp[r] = s;
      }
    }

    // R) rotate the x double-buffer (16 v_mov in the shadow).
    if (pf) {
#pragma unroll
      for (int k = 0; k < 4; ++k) xnP[k] = xnN[k];
    }
  }
}

// ---------------------------------------------------------------------------
// Workspace layout (bytes): [0, 16K) : hbuf[2][1024] tagged u64 (memset 0)
// ---------------------------------------------------------------------------
extern "C" void kernel_launch(void* const* d_in, const int* in_sizes, int n_in,
                              void* d_out, int out_size, void* d_ws, size_t ws_size,
                              hipStream_t stream) {
  (void)in_sizes; (void)n_in; (void)out_size; (void)ws_size;

  const float* x     = (const float*)d_in[0];  // [T,1,IN]
  const float* W_w   = (const float*)d_in[1];  // [4096, 2048]
  const float* W_b   = (const float*)d_in[2];  // [4096]
  const float* out_w = (const float*)d_in[3];  // [1024, 1024]
  const float* out_b = (const float*)d_in[4];  // [1024]
  float* out = (float*)d_out;                  // [T,1,1024]

  unsigned long long* hbuf = (unsigned long long*)d_ws;
  hipMemsetAsync(d_ws, 0, 16384, stream);

  lstm_fused<<<NBLK, TPB, 0, stream>>>(W_w, x, out_w, W_b, out_b, hbuf, out);
}